// Round 2
// 355.391 us; speedup vs baseline: 1.0248x; 1.0248x over previous
//
#include <hip/hip_runtime.h>

#define BB 1024
#define TB 512
#define FB 64
#define NH1 32
#define NH2 16
#define ND1 16
#define ND2 8

#define RD 16              // ring depth in steps (4 chunks)
#define RDM (RD - 1)
#define CHUNK 4            // steps per barrier period
#define NCH (TB / CHUNK)   // 128 chunks

// Wavefront-scope fence: runtime-free compiler barrier against LDS motion
// across masked-publish -> cross-lane-read handoffs.
#define WAVE_FENCE() __builtin_amdgcn_fence(__ATOMIC_ACQ_REL, "wavefront")

__device__ __forceinline__ float tanh_fast(float v) {
    // tanh(x) = 1 - 2/(e^{2x}+1); exp inf/0 limits give exactly +-1.
    float e = __expf(2.0f * v);
    return fmaf(-2.0f, __builtin_amdgcn_rcpf(e + 1.0f), 1.0f);
}

// Register-to-register cross-lane gather: lane reads `src` from lane (addr>>2).
__device__ __forceinline__ float bpermf(int byteAddr, int srcBits) {
    return __int_as_float(__builtin_amdgcn_ds_bpermute(byteAddr, srcBits));
}

// 3 waves per block, wave-specialized pipeline with uniform barrier schedule:
//   iter c: wave0 produces xp chunk c | wave1 runs L1 chunk c-1 | wave2 runs
//   L2 chunk c-2, then ONE __syncthreads(). All waves run NCH+2 iterations ->
//   identical barrier counts -> no deadlock possible (no spin-waits anywhere).
__global__ __attribute__((amdgpu_flat_work_group_size(192, 192)))
           __attribute__((amdgpu_waves_per_eu(3)))
void rnn_pipe_kernel(
    const float* __restrict__ x,
    const float* __restrict__ Wx1, const float* __restrict__ Wh1, const float* __restrict__ b1,
    const float* __restrict__ Wx2, const float* __restrict__ Wh2, const float* __restrict__ b2,
    const float* __restrict__ W3,  const float* __restrict__ b3,
    const float* __restrict__ W4,  const float* __restrict__ b4,
    const float* __restrict__ Wo,  const float* __restrict__ bo,
    float* __restrict__ out)
{
    __shared__ __align__(16) float xs[4][FB];        // wave0-private x_t staging ring
    __shared__ __align__(16) float xpring[RD][NH1];  // xp ring: wave0 -> wave1
    __shared__ __align__(16) float h1ring[RD][NH1];  // h1 ring: wave1 -> wave2
    __shared__ __align__(16) float h2s[NH2];         // head temp (wave2 only)
    __shared__ __align__(16) float ys[ND1];          // head temp (wave2 only)

    const int tid  = threadIdx.x;
    const int wid  = tid >> 6;
    const int lane = tid & 63;
    const int h = lane & 31;   // layer-1 output unit
    const int p = lane >> 5;   // half (0,1): input split for layer 1
    const int g = lane & 15;   // layer-2 output unit
    const int q = lane >> 4;   // quarter (0..3): h1-input split for layer 2
    const int b = blockIdx.x;

    if (wid == 0) {
        // ================= wave 0: xp producer (parallel work only) ==========
        auto w1 = [&](int i) { return Wx1[(32 * p + i) * NH1 + h]; };
        const float4 wxa = make_float4(w1(0),  w1(1),  w1(2),  w1(3));
        const float4 wxb = make_float4(w1(4),  w1(5),  w1(6),  w1(7));
        const float4 wxc = make_float4(w1(8),  w1(9),  w1(10), w1(11));
        const float4 wxd = make_float4(w1(12), w1(13), w1(14), w1(15));
        const float4 wxe = make_float4(w1(16), w1(17), w1(18), w1(19));
        const float4 wxf = make_float4(w1(20), w1(21), w1(22), w1(23));
        const float4 wxg = make_float4(w1(24), w1(25), w1(26), w1(27));
        const float4 wxh = make_float4(w1(28), w1(29), w1(30), w1(31));
        const float b1v = (p == 0) ? b1[h] : 0.0f;  // added once (pre-reduce mask)

        const float* xb = x + (size_t)b * TB * FB + lane;
        float xq0 = xb[0 * FB];
        float xq1 = xb[1 * FB];
        float xq2 = xb[2 * FB];
        float xq3 = xb[3 * FB];
        xs[0][lane] = xq0;

// Stage x_{t+1} (queued), consume x_t (staged last step), emit xp[t] to ring.
// The refill's vmcnt wait lands 4 steps later at its staging ds_write.
#define PSTEP(T, SLOT, QSTAGE, QREFILL)                                        \
    {                                                                          \
        WAVE_FENCE();                                                          \
        const int t_ = (T);                                                    \
        int tn_ = t_ + 4; tn_ = (tn_ < TB) ? tn_ : (TB - 1);                   \
        const float xnew_ = xb[(size_t)tn_ * FB];                              \
        xs[((SLOT) + 1) & 3][lane] = QSTAGE;                                   \
        const float4* xv = (const float4*)&xs[SLOT][32 * p];                   \
        float a0 = b1v, a1 = 0.0f, a2 = 0.0f, a3 = 0.0f;                       \
        float4 v_;                                                             \
        v_ = xv[0]; a0 = fmaf(v_.x, wxa.x, a0); a1 = fmaf(v_.y, wxa.y, a1);    \
                    a2 = fmaf(v_.z, wxa.z, a2); a3 = fmaf(v_.w, wxa.w, a3);    \
        v_ = xv[1]; a0 = fmaf(v_.x, wxb.x, a0); a1 = fmaf(v_.y, wxb.y, a1);    \
                    a2 = fmaf(v_.z, wxb.z, a2); a3 = fmaf(v_.w, wxb.w, a3);    \
        v_ = xv[2]; a0 = fmaf(v_.x, wxc.x, a0); a1 = fmaf(v_.y, wxc.y, a1);    \
                    a2 = fmaf(v_.z, wxc.z, a2); a3 = fmaf(v_.w, wxc.w, a3);    \
        v_ = xv[3]; a0 = fmaf(v_.x, wxd.x, a0); a1 = fmaf(v_.y, wxd.y, a1);    \
                    a2 = fmaf(v_.z, wxd.z, a2); a3 = fmaf(v_.w, wxd.w, a3);    \
        v_ = xv[4]; a0 = fmaf(v_.x, wxe.x, a0); a1 = fmaf(v_.y, wxe.y, a1);    \
                    a2 = fmaf(v_.z, wxe.z, a2); a3 = fmaf(v_.w, wxe.w, a3);    \
        v_ = xv[5]; a0 = fmaf(v_.x, wxf.x, a0); a1 = fmaf(v_.y, wxf.y, a1);    \
                    a2 = fmaf(v_.z, wxf.z, a2); a3 = fmaf(v_.w, wxf.w, a3);    \
        v_ = xv[6]; a0 = fmaf(v_.x, wxg.x, a0); a1 = fmaf(v_.y, wxg.y, a1);    \
                    a2 = fmaf(v_.z, wxg.z, a2); a3 = fmaf(v_.w, wxg.w, a3);    \
        v_ = xv[7]; a0 = fmaf(v_.x, wxh.x, a0); a1 = fmaf(v_.y, wxh.y, a1);    \
                    a2 = fmaf(v_.z, wxh.z, a2); a3 = fmaf(v_.w, wxh.w, a3);    \
        float acc = (a0 + a1) + (a2 + a3);                                     \
        acc += __shfl_xor(acc, 32, 64);                                        \
        WAVE_FENCE();                                                          \
        if (p == 0) xpring[t_ & RDM][h] = acc;                                 \
        QREFILL = xnew_;                                                       \
    }

        for (int c = 0; c < NCH + 2; ++c) {
            if (c < NCH) {
                const int t0 = c * CHUNK;
                PSTEP(t0 + 0, 0, xq1, xq0);
                PSTEP(t0 + 1, 1, xq2, xq1);
                PSTEP(t0 + 2, 2, xq3, xq2);
                PSTEP(t0 + 3, 3, xq0, xq3);
            }
            __syncthreads();
        }
#undef PSTEP

    } else if (wid == 1) {
        // ========== wave 1: L1 recurrence, register-resident chain ==========
        // After the cross-half reduce every lane holds h1[lane&31]; next step
        // gathers its 16 inputs with ds_bpermute (reg->reg, no LDS roundtrip).
        auto r1 = [&](int i) { return Wh1[(16 * p + i) * NH1 + h]; };
        const float4 wha = make_float4(r1(0),  r1(1),  r1(2),  r1(3));
        const float4 whb = make_float4(r1(4),  r1(5),  r1(6),  r1(7));
        const float4 whc = make_float4(r1(8),  r1(9),  r1(10), r1(11));
        const float4 whd = make_float4(r1(12), r1(13), r1(14), r1(15));
        const int bpb = 64 * p;   // byte base: source lanes 16p..16p+15
        float h1prev = 0.0f;      // h1_{-1} = 0

#define L1S(xpv, T)                                                            \
    {                                                                          \
        const int hh_ = __float_as_int(h1prev);                                \
        float a0 = 0.0f, a1 = 0.0f, a2 = 0.0f, a3 = 0.0f;                      \
        a0 = fmaf(bpermf(bpb +  0, hh_), wha.x, a0);                           \
        a1 = fmaf(bpermf(bpb +  4, hh_), wha.y, a1);                           \
        a2 = fmaf(bpermf(bpb +  8, hh_), wha.z, a2);                           \
        a3 = fmaf(bpermf(bpb + 12, hh_), wha.w, a3);                           \
        a0 = fmaf(bpermf(bpb + 16, hh_), whb.x, a0);                           \
        a1 = fmaf(bpermf(bpb + 20, hh_), whb.y, a1);                           \
        a2 = fmaf(bpermf(bpb + 24, hh_), whb.z, a2);                           \
        a3 = fmaf(bpermf(bpb + 28, hh_), whb.w, a3);                           \
        a0 = fmaf(bpermf(bpb + 32, hh_), whc.x, a0);                           \
        a1 = fmaf(bpermf(bpb + 36, hh_), whc.y, a1);                           \
        a2 = fmaf(bpermf(bpb + 40, hh_), whc.z, a2);                           \
        a3 = fmaf(bpermf(bpb + 44, hh_), whc.w, a3);                           \
        a0 = fmaf(bpermf(bpb + 48, hh_), whd.x, a0);                           \
        a1 = fmaf(bpermf(bpb + 52, hh_), whd.y, a1);                           \
        a2 = fmaf(bpermf(bpb + 56, hh_), whd.z, a2);                           \
        a3 = fmaf(bpermf(bpb + 60, hh_), whd.w, a3);                           \
        float acc = (a0 + a1) + (a2 + a3);                                     \
        acc += p ? 0.0f : (xpv);   /* xp (incl. b1) counted once */            \
        acc += __shfl_xor(acc, 32, 64);                                        \
        h1prev = tanh_fast(acc);                                               \
        WAVE_FENCE();                                                          \
        if (p == 0) h1ring[(T) & RDM][h] = h1prev;   /* publish to wave2 */    \
        WAVE_FENCE();                                                          \
    }

        for (int c = 0; c < NCH + 2; ++c) {
            if (c >= 1 && c <= NCH) {
                const int t0 = (c - 1) * CHUNK;
                float xp0 = xpring[(t0 + 0) & RDM][h];
                float xp1 = xpring[(t0 + 1) & RDM][h];
                float xp2 = xpring[(t0 + 2) & RDM][h];
                float xp3 = xpring[(t0 + 3) & RDM][h];
                L1S(xp0, t0 + 0);
                L1S(xp1, t0 + 1);
                L1S(xp2, t0 + 2);
                L1S(xp3, t0 + 3);
            }
            __syncthreads();
        }
#undef L1S

    } else {
        // ========= wave 2: L2 recurrence (register h2) + dense head =========
        auto w2 = [&](int i) { return Wx2[(8 * q + i) * NH2 + g]; };
        const float4 x2a = make_float4(w2(0), w2(1), w2(2), w2(3));
        const float4 x2b = make_float4(w2(4), w2(5), w2(6), w2(7));
        auto r2 = [&](int i) { return Wh2[i * NH2 + g]; };
        const float4 wh2a = make_float4(r2(0),  r2(1),  r2(2),  r2(3));
        const float4 wh2b = make_float4(r2(4),  r2(5),  r2(6),  r2(7));
        const float4 wh2c = make_float4(r2(8),  r2(9),  r2(10), r2(11));
        const float4 wh2d = make_float4(r2(12), r2(13), r2(14), r2(15));
        const float b2v = (q == 0) ? b2[g] : 0.0f;  // added once (pre-reduce mask)
        float h2prev = 0.0f;                        // h2_{-1} = 0

// cu (h1 input part) is independent of h2prev -> off the serial chain.
// h2 part: every lane holds h2prev[lane&15]; gather all 16 via uniform-addr
// bpermute (lane j < 16 broadcast), full dot per lane -> NO reduce on chain.
#define L2S(T)                                                                 \
    {                                                                          \
        const float* hr_ = &h1ring[(T) & RDM][8 * q];                          \
        float4 u0 = *(const float4*)(hr_);                                     \
        float4 u1 = *(const float4*)(hr_ + 4);                                 \
        float cu0 = b2v, cu1 = 0.0f;                                           \
        cu0 = fmaf(u0.x, x2a.x, cu0); cu1 = fmaf(u0.y, x2a.y, cu1);            \
        cu0 = fmaf(u0.z, x2a.z, cu0); cu1 = fmaf(u0.w, x2a.w, cu1);            \
        cu0 = fmaf(u1.x, x2b.x, cu0); cu1 = fmaf(u1.y, x2b.y, cu1);            \
        cu0 = fmaf(u1.z, x2b.z, cu0); cu1 = fmaf(u1.w, x2b.w, cu1);            \
        float cu = cu0 + cu1;                                                  \
        cu += __shfl_xor(cu, 16, 64);                                          \
        cu += __shfl_xor(cu, 32, 64);                                          \
        const int h2i_ = __float_as_int(h2prev);                               \
        float c0 = 0.0f, c1 = 0.0f, c2 = 0.0f, c3 = 0.0f;                      \
        c0 = fmaf(bpermf( 0, h2i_), wh2a.x, c0);                               \
        c1 = fmaf(bpermf( 4, h2i_), wh2a.y, c1);                               \
        c2 = fmaf(bpermf( 8, h2i_), wh2a.z, c2);                               \
        c3 = fmaf(bpermf(12, h2i_), wh2a.w, c3);                               \
        c0 = fmaf(bpermf(16, h2i_), wh2b.x, c0);                               \
        c1 = fmaf(bpermf(20, h2i_), wh2b.y, c1);                               \
        c2 = fmaf(bpermf(24, h2i_), wh2b.z, c2);                               \
        c3 = fmaf(bpermf(28, h2i_), wh2b.w, c3);                               \
        c0 = fmaf(bpermf(32, h2i_), wh2c.x, c0);                               \
        c1 = fmaf(bpermf(36, h2i_), wh2c.y, c1);                               \
        c2 = fmaf(bpermf(40, h2i_), wh2c.z, c2);                               \
        c3 = fmaf(bpermf(44, h2i_), wh2c.w, c3);                               \
        c0 = fmaf(bpermf(48, h2i_), wh2d.x, c0);                               \
        c1 = fmaf(bpermf(52, h2i_), wh2d.y, c1);                               \
        c2 = fmaf(bpermf(56, h2i_), wh2d.z, c2);                               \
        c3 = fmaf(bpermf(60, h2i_), wh2d.w, c3);                               \
        float ch = (c0 + c1) + (c2 + c3);                                      \
        h2prev = tanh_fast(cu + ch);                                           \
    }

        for (int c = 0; c < NCH + 2; ++c) {
            if (c >= 2) {
                const int t0 = (c - 2) * CHUNK;
                L2S(t0 + 0);
                L2S(t0 + 1);
                L2S(t0 + 2);
                L2S(t0 + 3);
            }
            __syncthreads();
        }
#undef L2S

        // ---- dense head (wave2 only; no further barriers needed) ----
        WAVE_FENCE();
        if (lane < NH2) h2s[lane] = h2prev;   // lane<16 holds h2[lane]
        WAVE_FENCE();

        float a3h = b3[g];
#pragma unroll
        for (int j = 0; j < 16; ++j) a3h = fmaf(h2s[j], W3[j * ND1 + g], a3h);
        float y1 = fmaxf(a3h, 0.0f);
        WAVE_FENCE();
        if (lane < ND1) ys[lane] = y1;
        WAVE_FENCE();

        const int e = lane & 7;
        float a4 = b4[e];
#pragma unroll
        for (int j = 0; j < 16; ++j) a4 = fmaf(ys[j], W4[j * ND2 + e], a4);

        float yo = a4 * Wo[e];
        yo += __shfl_xor(yo, 1, 64);
        yo += __shfl_xor(yo, 2, 64);
        yo += __shfl_xor(yo, 4, 64);
        if (lane == 0) out[b] = yo + bo[0];
    }
}

extern "C" void kernel_launch(void* const* d_in, const int* in_sizes, int n_in,
                              void* d_out, int out_size, void* d_ws, size_t ws_size,
                              hipStream_t stream) {
    const float* x   = (const float*)d_in[0];
    const float* Wx1 = (const float*)d_in[1];
    const float* Wh1 = (const float*)d_in[2];
    const float* b1  = (const float*)d_in[3];
    const float* Wx2 = (const float*)d_in[4];
    const float* Wh2 = (const float*)d_in[5];
    const float* b2  = (const float*)d_in[6];
    const float* W3  = (const float*)d_in[7];
    const float* b3  = (const float*)d_in[8];
    const float* W4  = (const float*)d_in[9];
    const float* b4  = (const float*)d_in[10];
    const float* Wo  = (const float*)d_in[11];
    const float* bo  = (const float*)d_in[12];
    float* out = (float*)d_out;

    rnn_pipe_kernel<<<dim3(BB), dim3(192), 0, stream>>>(
        x, Wx1, Wh1, b1, Wx2, Wh2, b2, W3, b3, W4, b4, Wo, bo, out);
}

// Round 3
// 335.118 us; speedup vs baseline: 1.0868x; 1.0605x over previous
//
#include <hip/hip_runtime.h>

#define BB 1024
#define TB 512
#define FB 64
#define NH1 32
#define NH2 16
#define ND1 16
#define ND2 8

#define RD 16              // ring depth in steps (2 chunks)
#define RDM (RD - 1)
#define CHUNK 8            // steps per barrier period
#define NCH (TB / CHUNK)   // 64 chunks

// Wavefront-scope fence: runtime-free compiler barrier against LDS motion
// across masked-publish -> read handoffs (DS pipe is in-order per wave, so
// only compiler reordering needs suppressing).
#define WAVE_FENCE() __builtin_amdgcn_fence(__ATOMIC_ACQ_REL, "wavefront")

__device__ __forceinline__ float tanh_fast(float v) {
    // tanh(x) = 1 - 2/(e^{2x}+1); exp inf/0 limits give exactly +-1.
    float e = __expf(2.0f * v);
    return fmaf(-2.0f, __builtin_amdgcn_rcpf(e + 1.0f), 1.0f);
}

// 3 waves per block, wave-specialized pipeline with uniform barrier schedule:
//   iter c: wave0 produces xp chunk c | wave1 runs L1 chunk c-1 | wave2 runs
//   L2 chunk c-2, then ONE __syncthreads(). All waves run NCH+2 iterations ->
//   identical barrier counts -> no deadlock possible (no spin-waits).
// All cross-lane traffic is LDS broadcast reads (1-2 bank-cycles) or masked
// 32-lane writes; NO ds_bpermute (wave64 bpermute ~6-8 DS-cycles was the
// round-2 bottleneck: 4 blocks/CU saturated the shared DS pipe).
__global__ __attribute__((amdgpu_flat_work_group_size(192, 192)))
           __attribute__((amdgpu_waves_per_eu(3)))
void rnn_pipe_kernel(
    const float* __restrict__ x,
    const float* __restrict__ Wx1, const float* __restrict__ Wh1, const float* __restrict__ b1,
    const float* __restrict__ Wx2, const float* __restrict__ Wh2, const float* __restrict__ b2,
    const float* __restrict__ W3,  const float* __restrict__ b3,
    const float* __restrict__ W4,  const float* __restrict__ b4,
    const float* __restrict__ Wo,  const float* __restrict__ bo,
    float* __restrict__ out)
{
    __shared__ __align__(16) float xs[CHUNK][FB];    // wave0-private x staging
    __shared__ __align__(16) float xpring[RD][NH1];  // xp ring: wave0 -> wave1
    __shared__ __align__(16) float h1ring[RD][NH1];  // h1 ring: wave1 -> wave1/wave2
    __shared__ __align__(16) float h2s[NH2];         // h2 state (wave2 only)
    __shared__ __align__(16) float ys[ND1];          // head temp (wave2 only)

    const int tid  = threadIdx.x;
    const int wid  = tid >> 6;
    const int lane = tid & 63;
    const int h = lane & 31;   // layer-1 output unit
    const int p = lane >> 5;   // half (0,1): input split for layer-1 xp
    const int g = lane & 15;   // layer-2 output unit
    const int q = lane >> 4;   // quarter (0..3): h1-input split for layer-2 cu
    const int b = blockIdx.x;

    if (wid == 0) {
        // ================= wave 0: xp producer (parallel work only) ==========
        auto w1 = [&](int i) { return Wx1[(32 * p + i) * NH1 + h]; };
        const float4 wxa = make_float4(w1(0),  w1(1),  w1(2),  w1(3));
        const float4 wxb = make_float4(w1(4),  w1(5),  w1(6),  w1(7));
        const float4 wxc = make_float4(w1(8),  w1(9),  w1(10), w1(11));
        const float4 wxd = make_float4(w1(12), w1(13), w1(14), w1(15));
        const float4 wxe = make_float4(w1(16), w1(17), w1(18), w1(19));
        const float4 wxf = make_float4(w1(20), w1(21), w1(22), w1(23));
        const float4 wxg = make_float4(w1(24), w1(25), w1(26), w1(27));
        const float4 wxh = make_float4(w1(28), w1(29), w1(30), w1(31));
        const float b1v = (p == 0) ? b1[h] : 0.0f;  // added once (pre-reduce mask)

        const float* xb = x + (size_t)b * TB * FB + lane;
        // prefetch chunk 0
        float xq0 = xb[0 * FB];
        float xq1 = xb[1 * FB];
        float xq2 = xb[2 * FB];
        float xq3 = xb[3 * FB];
        float xq4 = xb[4 * FB];
        float xq5 = xb[5 * FB];
        float xq6 = xb[6 * FB];
        float xq7 = xb[7 * FB];

#define XPSTEP(S, T0)                                                          \
    {                                                                          \
        const int t_ = (T0) + (S);                                             \
        const float4* xv = (const float4*)&xs[S][32 * p];                      \
        float a0 = b1v, a1 = 0.0f, a2 = 0.0f, a3 = 0.0f;                       \
        float4 v_;                                                             \
        v_ = xv[0]; a0 = fmaf(v_.x, wxa.x, a0); a1 = fmaf(v_.y, wxa.y, a1);    \
                    a2 = fmaf(v_.z, wxa.z, a2); a3 = fmaf(v_.w, wxa.w, a3);    \
        v_ = xv[1]; a0 = fmaf(v_.x, wxb.x, a0); a1 = fmaf(v_.y, wxb.y, a1);    \
                    a2 = fmaf(v_.z, wxb.z, a2); a3 = fmaf(v_.w, wxb.w, a3);    \
        v_ = xv[2]; a0 = fmaf(v_.x, wxc.x, a0); a1 = fmaf(v_.y, wxc.y, a1);    \
                    a2 = fmaf(v_.z, wxc.z, a2); a3 = fmaf(v_.w, wxc.w, a3);    \
        v_ = xv[3]; a0 = fmaf(v_.x, wxd.x, a0); a1 = fmaf(v_.y, wxd.y, a1);    \
                    a2 = fmaf(v_.z, wxd.z, a2); a3 = fmaf(v_.w, wxd.w, a3);    \
        v_ = xv[4]; a0 = fmaf(v_.x, wxe.x, a0); a1 = fmaf(v_.y, wxe.y, a1);    \
                    a2 = fmaf(v_.z, wxe.z, a2); a3 = fmaf(v_.w, wxe.w, a3);    \
        v_ = xv[5]; a0 = fmaf(v_.x, wxf.x, a0); a1 = fmaf(v_.y, wxf.y, a1);    \
                    a2 = fmaf(v_.z, wxf.z, a2); a3 = fmaf(v_.w, wxf.w, a3);    \
        v_ = xv[6]; a0 = fmaf(v_.x, wxg.x, a0); a1 = fmaf(v_.y, wxg.y, a1);    \
                    a2 = fmaf(v_.z, wxg.z, a2); a3 = fmaf(v_.w, wxg.w, a3);    \
        v_ = xv[7]; a0 = fmaf(v_.x, wxh.x, a0); a1 = fmaf(v_.y, wxh.y, a1);    \
                    a2 = fmaf(v_.z, wxh.z, a2); a3 = fmaf(v_.w, wxh.w, a3);    \
        float acc = (a0 + a1) + (a2 + a3);                                     \
        acc += __shfl_xor(acc, 32, 64);                                        \
        WAVE_FENCE();                                                          \
        if (p == 0) xpring[t_ & RDM][h] = acc;                                 \
    }

        for (int c = 0; c < NCH + 2; ++c) {
            if (c < NCH) {
                const int t0 = c * CHUNK;
                // stage regs loaded last chunk (vmcnt already drained at barrier)
                xs[0][lane] = xq0;
                xs[1][lane] = xq1;
                xs[2][lane] = xq2;
                xs[3][lane] = xq3;
                xs[4][lane] = xq4;
                xs[5][lane] = xq5;
                xs[6][lane] = xq6;
                xs[7][lane] = xq7;
                // issue next chunk's loads early: whole chunk covers latency
                {
                    const int nb = (c + 1) * CHUNK;
                    int n0 = nb + 0; n0 = (n0 < TB) ? n0 : (TB - 1);
                    int n1 = nb + 1; n1 = (n1 < TB) ? n1 : (TB - 1);
                    int n2 = nb + 2; n2 = (n2 < TB) ? n2 : (TB - 1);
                    int n3 = nb + 3; n3 = (n3 < TB) ? n3 : (TB - 1);
                    int n4 = nb + 4; n4 = (n4 < TB) ? n4 : (TB - 1);
                    int n5 = nb + 5; n5 = (n5 < TB) ? n5 : (TB - 1);
                    int n6 = nb + 6; n6 = (n6 < TB) ? n6 : (TB - 1);
                    int n7 = nb + 7; n7 = (n7 < TB) ? n7 : (TB - 1);
                    xq0 = xb[(size_t)n0 * FB];
                    xq1 = xb[(size_t)n1 * FB];
                    xq2 = xb[(size_t)n2 * FB];
                    xq3 = xb[(size_t)n3 * FB];
                    xq4 = xb[(size_t)n4 * FB];
                    xq5 = xb[(size_t)n5 * FB];
                    xq6 = xb[(size_t)n6 * FB];
                    xq7 = xb[(size_t)n7 * FB];
                }
                XPSTEP(0, t0); XPSTEP(1, t0); XPSTEP(2, t0); XPSTEP(3, t0);
                XPSTEP(4, t0); XPSTEP(5, t0); XPSTEP(6, t0); XPSTEP(7, t0);
            }
            __syncthreads();
        }
#undef XPSTEP

    } else if (wid == 1) {
        // ========== wave 1: L1 recurrence (the true serial chain) ===========
        // Full 32-term dot per lane from UNIFORM-address b128 reads of the
        // h1 ring row (broadcast, ~1-2 DS-cy each) -> no bpermute, no reduce
        // shuffle on the chain. All 64 lanes compute h=lane&31 redundantly.
        auto r1f = [&](int j) { return Wh1[j * NH1 + h]; };
        const float4 whA = make_float4(r1f(0),  r1f(1),  r1f(2),  r1f(3));
        const float4 whB = make_float4(r1f(4),  r1f(5),  r1f(6),  r1f(7));
        const float4 whC = make_float4(r1f(8),  r1f(9),  r1f(10), r1f(11));
        const float4 whD = make_float4(r1f(12), r1f(13), r1f(14), r1f(15));
        const float4 whE = make_float4(r1f(16), r1f(17), r1f(18), r1f(19));
        const float4 whF = make_float4(r1f(20), r1f(21), r1f(22), r1f(23));
        const float4 whG = make_float4(r1f(24), r1f(25), r1f(26), r1f(27));
        const float4 whH = make_float4(r1f(28), r1f(29), r1f(30), r1f(31));

        if (p == 0) h1ring[RDM][h] = 0.0f;   // h1_{-1} = 0 (slot (0-1)&15)

#define L1S(S, T0)                                                             \
    {                                                                          \
        const int t_ = (T0) + (S);                                             \
        float xpv = xpring[t_ & RDM][h];                                       \
        const float4* hr = (const float4*)&h1ring[(t_ - 1) & RDM][0];          \
        float4 r0 = hr[0], r1 = hr[1], r2 = hr[2], r3 = hr[3];                 \
        float4 r4 = hr[4], r5 = hr[5], r6 = hr[6], r7 = hr[7];                 \
        float a0 = xpv,  a1 = 0.0f, a2 = 0.0f, a3 = 0.0f;                      \
        float a4 = 0.0f, a5 = 0.0f, a6 = 0.0f, a7 = 0.0f;                      \
        a0 = fmaf(r0.x, whA.x, a0); a1 = fmaf(r0.y, whA.y, a1);                \
        a2 = fmaf(r0.z, whA.z, a2); a3 = fmaf(r0.w, whA.w, a3);                \
        a4 = fmaf(r1.x, whB.x, a4); a5 = fmaf(r1.y, whB.y, a5);                \
        a6 = fmaf(r1.z, whB.z, a6); a7 = fmaf(r1.w, whB.w, a7);                \
        a0 = fmaf(r2.x, whC.x, a0); a1 = fmaf(r2.y, whC.y, a1);                \
        a2 = fmaf(r2.z, whC.z, a2); a3 = fmaf(r2.w, whC.w, a3);                \
        a4 = fmaf(r3.x, whD.x, a4); a5 = fmaf(r3.y, whD.y, a5);                \
        a6 = fmaf(r3.z, whD.z, a6); a7 = fmaf(r3.w, whD.w, a7);                \
        a0 = fmaf(r4.x, whE.x, a0); a1 = fmaf(r4.y, whE.y, a1);                \
        a2 = fmaf(r4.z, whE.z, a2); a3 = fmaf(r4.w, whE.w, a3);                \
        a4 = fmaf(r5.x, whF.x, a4); a5 = fmaf(r5.y, whF.y, a5);                \
        a6 = fmaf(r5.z, whF.z, a6); a7 = fmaf(r5.w, whF.w, a7);                \
        a0 = fmaf(r6.x, whG.x, a0); a1 = fmaf(r6.y, whG.y, a1);                \
        a2 = fmaf(r6.z, whG.z, a2); a3 = fmaf(r6.w, whG.w, a3);                \
        a4 = fmaf(r7.x, whH.x, a4); a5 = fmaf(r7.y, whH.y, a5);                \
        a6 = fmaf(r7.z, whH.z, a6); a7 = fmaf(r7.w, whH.w, a7);                \
        float acc = ((a0 + a1) + (a2 + a3)) + ((a4 + a5) + (a6 + a7));         \
        float h1new = tanh_fast(acc);                                          \
        WAVE_FENCE();                                                          \
        if (p == 0) h1ring[t_ & RDM][h] = h1new;                               \
        WAVE_FENCE();                                                          \
    }

        for (int c = 0; c < NCH + 2; ++c) {
            if (c >= 1 && c <= NCH) {
                const int t0 = (c - 1) * CHUNK;
                L1S(0, t0); L1S(1, t0); L1S(2, t0); L1S(3, t0);
                L1S(4, t0); L1S(5, t0); L1S(6, t0); L1S(7, t0);
            }
            __syncthreads();
        }
#undef L1S

    } else {
        // ========= wave 2: L2 recurrence (LDS h2 state) + dense head =========
        auto w2f = [&](int i) { return Wx2[(8 * q + i) * NH2 + g]; };
        const float4 o2a = make_float4(w2f(0), w2f(1), w2f(2), w2f(3));
        const float4 o2b = make_float4(w2f(4), w2f(5), w2f(6), w2f(7));
        auto r2f = [&](int j) { return Wh2[j * NH2 + g]; };
        const float4 w2A = make_float4(r2f(0),  r2f(1),  r2f(2),  r2f(3));
        const float4 w2B = make_float4(r2f(4),  r2f(5),  r2f(6),  r2f(7));
        const float4 w2C = make_float4(r2f(8),  r2f(9),  r2f(10), r2f(11));
        const float4 w2D = make_float4(r2f(12), r2f(13), r2f(14), r2f(15));
        const float b2v = (q == 0) ? b2[g] : 0.0f;  // added once (pre-reduce mask)

        if (lane < NH2) h2s[lane] = 0.0f;   // h2_{-1} = 0

// cu (h1-input part, 4-way split + 2 shuffles) is independent of h2 state ->
// off the recurrence chain. ch (h2 part) is a full 16-term dot per lane from
// uniform b128 broadcast reads of h2s -> chain = read + 16 FMA + tanh + write.
#define L2S(S, T0)                                                             \
    {                                                                          \
        const int t_ = (T0) + (S);                                             \
        const float* hrow = &h1ring[t_ & RDM][8 * q];                          \
        float4 u0 = *(const float4*)(hrow);                                    \
        float4 u1 = *(const float4*)(hrow + 4);                                \
        const float4* hv = (const float4*)h2s;                                 \
        float4 v0 = hv[0], v1 = hv[1], v2 = hv[2], v3 = hv[3];                 \
        float cu0 = b2v, cu1 = 0.0f;                                           \
        cu0 = fmaf(u0.x, o2a.x, cu0); cu1 = fmaf(u0.y, o2a.y, cu1);            \
        cu0 = fmaf(u0.z, o2a.z, cu0); cu1 = fmaf(u0.w, o2a.w, cu1);            \
        cu0 = fmaf(u1.x, o2b.x, cu0); cu1 = fmaf(u1.y, o2b.y, cu1);            \
        cu0 = fmaf(u1.z, o2b.z, cu0); cu1 = fmaf(u1.w, o2b.w, cu1);            \
        float cu = cu0 + cu1;                                                  \
        cu += __shfl_xor(cu, 16, 64);                                          \
        cu += __shfl_xor(cu, 32, 64);                                          \
        float c0 = 0.0f, c1 = 0.0f, c2 = 0.0f, c3 = 0.0f;                      \
        c0 = fmaf(v0.x, w2A.x, c0); c1 = fmaf(v0.y, w2A.y, c1);                \
        c2 = fmaf(v0.z, w2A.z, c2); c3 = fmaf(v0.w, w2A.w, c3);                \
        c0 = fmaf(v1.x, w2B.x, c0); c1 = fmaf(v1.y, w2B.y, c1);                \
        c2 = fmaf(v1.z, w2B.z, c2); c3 = fmaf(v1.w, w2B.w, c3);                \
        c0 = fmaf(v2.x, w2C.x, c0); c1 = fmaf(v2.y, w2C.y, c1);                \
        c2 = fmaf(v2.z, w2C.z, c2); c3 = fmaf(v2.w, w2C.w, c3);                \
        c0 = fmaf(v3.x, w2D.x, c0); c1 = fmaf(v3.y, w2D.y, c1);                \
        c2 = fmaf(v3.z, w2D.z, c2); c3 = fmaf(v3.w, w2D.w, c3);                \
        float ch = (c0 + c1) + (c2 + c3);                                      \
        float h2new = tanh_fast(cu + ch);                                      \
        WAVE_FENCE();                                                          \
        if (lane < NH2) h2s[lane] = h2new;                                     \
        WAVE_FENCE();                                                          \
    }

        for (int c = 0; c < NCH + 2; ++c) {
            if (c >= 2) {
                const int t0 = (c - 2) * CHUNK;
                L2S(0, t0); L2S(1, t0); L2S(2, t0); L2S(3, t0);
                L2S(4, t0); L2S(5, t0); L2S(6, t0); L2S(7, t0);
            }
            __syncthreads();
        }
#undef L2S

        // ---- dense head (wave2 only; h2s already holds final h2) ----
        WAVE_FENCE();
        float a3h = b3[g];
#pragma unroll
        for (int j = 0; j < 16; ++j) a3h = fmaf(h2s[j], W3[j * ND1 + g], a3h);
        float y1 = fmaxf(a3h, 0.0f);
        WAVE_FENCE();
        if (lane < ND1) ys[lane] = y1;
        WAVE_FENCE();

        const int e = lane & 7;
        float a4 = b4[e];
#pragma unroll
        for (int j = 0; j < 16; ++j) a4 = fmaf(ys[j], W4[j * ND2 + e], a4);

        float yo = a4 * Wo[e];
        yo += __shfl_xor(yo, 1, 64);
        yo += __shfl_xor(yo, 2, 64);
        yo += __shfl_xor(yo, 4, 64);
        if (lane == 0) out[b] = yo + bo[0];
    }
}

extern "C" void kernel_launch(void* const* d_in, const int* in_sizes, int n_in,
                              void* d_out, int out_size, void* d_ws, size_t ws_size,
                              hipStream_t stream) {
    const float* x   = (const float*)d_in[0];
    const float* Wx1 = (const float*)d_in[1];
    const float* Wh1 = (const float*)d_in[2];
    const float* b1  = (const float*)d_in[3];
    const float* Wx2 = (const float*)d_in[4];
    const float* Wh2 = (const float*)d_in[5];
    const float* b2  = (const float*)d_in[6];
    const float* W3  = (const float*)d_in[7];
    const float* b3  = (const float*)d_in[8];
    const float* W4  = (const float*)d_in[9];
    const float* b4  = (const float*)d_in[10];
    const float* Wo  = (const float*)d_in[11];
    const float* bo  = (const float*)d_in[12];
    float* out = (float*)d_out;

    rnn_pipe_kernel<<<dim3(BB), dim3(192), 0, stream>>>(
        x, Wx1, Wh1, b1, Wx2, Wh2, b2, W3, b3, W4, b4, Wo, bo, out);
}